// Round 9
// baseline (4062.585 us; speedup 1.0000x reference)
//
#include <hip/hip_runtime.h>

#define B_ 8
#define N_ 32768
#define S_ 1024
#define C_ 96
#define T_ 512            // 8 waves, 2/SIMD; LDS (128 KiB) pins 1 block/CU
#define PK 32             // f2v pairs per thread (64 points)

typedef float f2v __attribute__((ext_vector_type(2)));

// d_out layout (float32, concatenated):
//   [0, B*S*3)                      new_xyz  (B,S,3)
//   [B*S*3, B*S*3+B*C*S)            new_fea  (B,C,S)
//   [B*S*3+B*C*S, +B*S)             indices  (B,S) as float

__global__ __launch_bounds__(T_)
__attribute__((amdgpu_waves_per_eu(2, 2)))
__attribute__((amdgpu_num_vgpr(256)))   // direct budget: 192 coord regs MUST be arch VGPRs
void fps_kernel(
    const float* __restrict__ xyz,   // (B, N, 3)
    float* __restrict__ out)
{
#pragma clang fp contract(off)
  const int b    = blockIdx.x;
  const int tid  = threadIdx.x;
  const int wv   = tid >> 6;        // wave 0..7
  const int lane = tid & 63;
  const float* xb = xyz + (size_t)b * N_ * 3;

  float* out_xyz = out;
  float* out_idx = out + (size_t)B_*S_*3 + (size_t)B_*C_*S_;

  // Running min sq-dists, thread-private f2v slots at s_dist2[k*T_ + tid]:
  // ds_read_b64/ds_write_b64, 128 dwords/wave-access -> perfectly bank-balanced.
  __shared__ f2v   s_dist2[N_/2];   // 128 KiB
  __shared__ float s_v[2][8];       // per-wave partials, parity double-buffered
  __shared__ int   s_i[2][8];

  // Coordinates in ARCH registers as f2v pairs (points 2k*T_+tid, (2k+1)*T_+tid).
  f2v X[PK], Y[PK], Z[PK];
  #pragma unroll
  for (int k = 0; k < PK; ++k) {
    const int g0 = (2*k)   * T_ + tid;
    const int g1 = (2*k+1) * T_ + tid;
    X[k] = (f2v){xb[g0*3+0], xb[g1*3+0]};
    Y[k] = (f2v){xb[g0*3+1], xb[g1*3+1]};
    Z[k] = (f2v){xb[g0*3+2], xb[g1*3+2]};
    s_dist2[k*T_ + tid] = (f2v){1e10f, 1e10f};
  }
  // Pin: asm-defined values are not rematerializable -> no reload "spills".
  #pragma unroll
  for (int k = 0; k < PK; ++k) {
    asm volatile("" : "+v"(X[k]), "+v"(Y[k]), "+v"(Z[k]));
  }
  // No barrier: each thread touches only its own s_dist2 slots.

  int cur = 0;
  for (int s = 0; s < S_; ++s) {
    // cur is block-uniform -> scalar loads for the broadcast coords.
    const int cu = __builtin_amdgcn_readfirstlane(cur);
    const float cx = xb[cu*3+0];
    const float cy = xb[cu*3+1];
    const float cz = xb[cu*3+2];
    if (tid == 0) {
      out_idx[(size_t)b*S_ + s] = (float)cu;
      float* o = out_xyz + ((size_t)b*S_ + s)*3;
      o[0] = cx; o[1] = cy; o[2] = cz;
    }
    const f2v c2x = (f2v){cx, cx};
    const f2v c2y = (f2v){cy, cy};
    const f2v c2z = (f2v){cz, cz};

    // Exact IEEE ((dx^2+dy^2)+dz^2), no contraction; per-thread argmax with
    // first-index tie-break (ascending k, strict >; idx(2k) < idx(2k+1)).
    float bv = -1.0f;
    int   bj = 0;
    #pragma unroll
    for (int k = 0; k < PK; ++k) {
      const int o2 = k * T_ + tid;
      const f2v od = s_dist2[o2];
      const f2v dx = X[k] - c2x;      // v_pk_add (neg mod)
      const f2v dy = Y[k] - c2y;
      const f2v dz = Z[k] - c2z;
      const f2v d  = (dx*dx + dy*dy) + dz*dz;   // pk_mul x3, pk_add x2
      f2v nd;
      nd.x = fminf(od.x, d.x);
      nd.y = fminf(od.y, d.y);
      s_dist2[o2] = nd;
      if (nd.x > bv) { bv = nd.x; bj = 2*k;   }
      if (nd.y > bv) { bv = nd.y; bj = 2*k+1; }
    }
    int bg = (bj << 9) + tid;        // global point index (T_ == 512)

    // In-wave argmax reduce, smallest-index ties.
    #pragma unroll
    for (int off = 32; off > 0; off >>= 1) {
      const float ov = __shfl_down(bv, off);
      const int   og = __shfl_down(bg, off);
      if (ov > bv || (ov == bv && og < bg)) { bv = ov; bg = og; }
    }
    const int par = s & 1;
    if (lane == 0) { s_v[par][wv] = bv; s_i[par][wv] = bg; }
    __syncthreads();   // single barrier/step (parity buffers make it race-free)

    // Every wave redundantly reduces the 8 partials -> winner in all lanes.
    float v = s_v[par][lane & 7];
    int   g = s_i[par][lane & 7];
    #pragma unroll
    for (int m = 4; m > 0; m >>= 1) {
      const float ov = __shfl_xor(v, m);
      const int   og = __shfl_xor(g, m);
      if (ov > v || (ov == v && og < g)) { v = ov; g = og; }
    }
    cur = g;
  }
}

__global__ void gather_fea_kernel(
    const float* __restrict__ feat,   // (B, C, N)
    const float* __restrict__ idxf,   // (B, S) float indices (in d_out)
    float* __restrict__ out_fea)      // (B, C, S)
{
  const int t = blockIdx.x * blockDim.x + threadIdx.x;
  if (t >= B_ * C_ * S_) return;
  const int s  = t & (S_ - 1);
  const int bc = t >> 10;           // S_ == 1024
  const int c  = bc % C_;
  const int b  = bc / C_;
  const int idx = (int)idxf[(size_t)b * S_ + s];
  out_fea[t] = feat[((size_t)b * C_ + c) * (size_t)N_ + idx];
}

extern "C" void kernel_launch(void* const* d_in, const int* in_sizes, int n_in,
                              void* d_out, int out_size, void* d_ws, size_t ws_size,
                              hipStream_t stream) {
  const float* xyz  = (const float*)d_in[0];   // (B,N,3)
  const float* feat = (const float*)d_in[1];   // (B,C,N)
  float* out = (float*)d_out;

  float* out_fea = out + (size_t)B_ * S_ * 3;
  float* out_idx = out + (size_t)B_ * S_ * 3 + (size_t)B_ * C_ * S_;
  (void)d_ws; (void)ws_size; (void)in_sizes; (void)n_in; (void)out_size;

  fps_kernel<<<B_, T_, 0, stream>>>(xyz, out);

  const int total = B_ * C_ * S_;
  gather_fea_kernel<<<(total + 255) / 256, 256, 0, stream>>>(feat, out_idx, out_fea);
}

// Round 10
// 3933.023 us; speedup vs baseline: 1.0329x; 1.0329x over previous
//
#include <hip/hip_runtime.h>

#define B_ 8
#define N_ 32768
#define S_ 1024
#define C_ 96
#define T_ 512            // 8 waves, 2/SIMD; LDS (128 KiB) pins 1 block/CU
#define PK 32             // f2v pairs per thread (64 points)

typedef float f2v __attribute__((ext_vector_type(2)));

// d_out layout (float32, concatenated):
//   [0, B*S*3)                      new_xyz  (B,S,3)
//   [B*S*3, B*S*3+B*C*S)            new_fea  (B,C,S)
//   [B*S*3+B*C*S, +B*S)             indices  (B,S) as float

__global__ __launch_bounds__(T_)
__attribute__((amdgpu_waves_per_eu(2, 2)))
void fps_kernel(
    const float* __restrict__ xyz,   // (B, N, 3)
    float* __restrict__ out)
{
#pragma clang fp contract(off)
  const int b    = blockIdx.x;
  const int tid  = threadIdx.x;
  const int wv   = tid >> 6;        // wave 0..7
  const int lane = tid & 63;
  const float* xb = xyz + (size_t)b * N_ * 3;

  float* out_xyz = out;
  float* out_idx = out + (size_t)B_*S_*3 + (size_t)B_*C_*S_;

  // Running min sq-dists, thread-private f2v slots at s_dist2[k*T_ + tid]:
  // ds_read_b64/ds_write_b64, 128 dwords/wave-access -> bank-balanced.
  __shared__ f2v   s_dist2[N_/2];   // 128 KiB
  __shared__ float s_v[2][8];       // per-wave partials, parity double-buffered
  __shared__ int   s_i[2][8];

  // Coordinates as f2v pairs (points 2k*T_+tid, (2k+1)*T_+tid).
  f2v X[PK], Y[PK], Z[PK];
  #pragma unroll
  for (int k = 0; k < PK; ++k) {
    const int g0 = (2*k)   * T_ + tid;
    const int g1 = (2*k+1) * T_ + tid;
    X[k] = (f2v){xb[g0*3+0], xb[g1*3+0]};
    Y[k] = (f2v){xb[g0*3+1], xb[g1*3+1]};
    Z[k] = (f2v){xb[g0*3+2], xb[g1*3+2]};
    s_dist2[k*T_ + tid] = (f2v){1e10f, 1e10f};
  }
  // Pin: asm-defined values are not rematerializable -> no reload "spills".
  #pragma unroll
  for (int k = 0; k < PK; ++k) {
    asm volatile("" : "+v"(X[k]), "+v"(Y[k]), "+v"(Z[k]));
  }
  // No barrier: each thread touches only its own s_dist2 slots.

  int cur = 0;
  for (int s = 0; s < S_; ++s) {
    // cur is block-uniform -> scalar loads for the broadcast coords.
    const int cu = __builtin_amdgcn_readfirstlane(cur);
    const float cx = xb[cu*3+0];
    const float cy = xb[cu*3+1];
    const float cz = xb[cu*3+2];
    if (tid == 0) {
      out_idx[(size_t)b*S_ + s] = (float)cur;
      float* o = out_xyz + ((size_t)b*S_ + s)*3;
      o[0] = cx; o[1] = cy; o[2] = cz;
    }
    // p - c computed as p + (-c): IEEE-identical (incl. signed zeros).
    const float ncx = -cx, ncy = -cy, ncz = -cz;
    const f2v nc2x = (f2v){ncx, ncx};
    const f2v nc2y = (f2v){ncy, ncy};
    const f2v nc2z = (f2v){ncz, ncz};

    // Min-dist update; pair-level argmax (value + pair id only in-loop).
    float bv = -1.0f;
    int   bjp = 0;
    #pragma unroll
    for (int k = 0; k < PK; ++k) {
      const int o2 = k * T_ + tid;
      const f2v od = s_dist2[o2];
      f2v dx, dy, dz, sx, sy, sz, s1, d;
      // Forced VOP3P packed fp32: one instruction per two points.
      asm("v_pk_add_f32 %0, %1, %2" : "=v"(dx) : "v"(X[k]), "v"(nc2x));
      asm("v_pk_add_f32 %0, %1, %2" : "=v"(dy) : "v"(Y[k]), "v"(nc2y));
      asm("v_pk_add_f32 %0, %1, %2" : "=v"(dz) : "v"(Z[k]), "v"(nc2z));
      asm("v_pk_mul_f32 %0, %1, %1" : "=v"(sx) : "v"(dx));
      asm("v_pk_mul_f32 %0, %1, %1" : "=v"(sy) : "v"(dy));
      asm("v_pk_mul_f32 %0, %1, %1" : "=v"(sz) : "v"(dz));
      asm("v_pk_add_f32 %0, %1, %2" : "=v"(s1) : "v"(sx), "v"(sy));   // dx^2+dy^2
      asm("v_pk_add_f32 %0, %1, %2" : "=v"(d)  : "v"(s1), "v"(sz));   // +dz^2 (np order)
      f2v nd;
      nd.x = fminf(od.x, d.x);
      nd.y = fminf(od.y, d.y);
      s_dist2[o2] = nd;
      const float m = fmaxf(nd.x, nd.y);
      if (m > bv) { bv = m; bjp = k; }    // strict > : earliest pair on ties
    }
    // Resolve which half of the winning pair: x-half (smaller global index)
    // preferred on intra-pair tie -> matches np.argmax first-occurrence.
    const f2v ndw = s_dist2[bjp * T_ + tid];
    const int bj  = 2*bjp + ((ndw.x == bv) ? 0 : 1);
    int bg = (bj << 9) + tid;        // global point index (T_ == 512)

    // In-wave argmax reduce, smallest-index ties.
    #pragma unroll
    for (int off = 32; off > 0; off >>= 1) {
      const float ov = __shfl_down(bv, off);
      const int   og = __shfl_down(bg, off);
      if (ov > bv || (ov == bv && og < bg)) { bv = ov; bg = og; }
    }
    const int par = s & 1;
    if (lane == 0) { s_v[par][wv] = bv; s_i[par][wv] = bg; }
    __syncthreads();   // single barrier/step (parity buffers make it race-free)

    // Every wave redundantly reduces the 8 partials -> winner in all lanes.
    float v = s_v[par][lane & 7];
    int   g = s_i[par][lane & 7];
    #pragma unroll
    for (int m = 4; m > 0; m >>= 1) {
      const float ov = __shfl_xor(v, m);
      const int   og = __shfl_xor(g, m);
      if (ov > v || (ov == v && og < g)) { v = ov; g = og; }
    }
    cur = g;
  }
}

__global__ void gather_fea_kernel(
    const float* __restrict__ feat,   // (B, C, N)
    const float* __restrict__ idxf,   // (B, S) float indices (in d_out)
    float* __restrict__ out_fea)      // (B, C, S)
{
  const int t = blockIdx.x * blockDim.x + threadIdx.x;
  if (t >= B_ * C_ * S_) return;
  const int s  = t & (S_ - 1);
  const int bc = t >> 10;           // S_ == 1024
  const int c  = bc % C_;
  const int b  = bc / C_;
  const int idx = (int)idxf[(size_t)b * S_ + s];
  out_fea[t] = feat[((size_t)b * C_ + c) * (size_t)N_ + idx];
}

extern "C" void kernel_launch(void* const* d_in, const int* in_sizes, int n_in,
                              void* d_out, int out_size, void* d_ws, size_t ws_size,
                              hipStream_t stream) {
  const float* xyz  = (const float*)d_in[0];   // (B,N,3)
  const float* feat = (const float*)d_in[1];   // (B,C,N)
  float* out = (float*)d_out;

  float* out_fea = out + (size_t)B_ * S_ * 3;
  float* out_idx = out + (size_t)B_ * S_ * 3 + (size_t)B_ * C_ * S_;
  (void)d_ws; (void)ws_size; (void)in_sizes; (void)n_in; (void)out_size;

  fps_kernel<<<B_, T_, 0, stream>>>(xyz, out);

  const int total = B_ * C_ * S_;
  gather_fea_kernel<<<(total + 255) / 256, 256, 0, stream>>>(feat, out_idx, out_fea);
}